// Round 5
// baseline (350.767 us; speedup 1.0000x reference)
//
#include <hip/hip_runtime.h>
#include <hip/hip_bf16.h>

#define BB 2
#define LL 5
#define HH 48
#define WW 48
#define CC 256
#define MM 8
#define DD 32
#define HWW (HH*WW)        // 2304
#define NTOK (BB*LL*HWW)   // 23040
#define INNER 256
#define NPROJ 768
#define SCALE_ATT 0.17677669529663687f

typedef __hip_bfloat16 bf16;
typedef short short8 __attribute__((ext_vector_type(8)));
typedef float f32x4  __attribute__((ext_vector_type(4)));

__device__ __forceinline__ float b2f(bf16 v){ return __bfloat162float(v); }
__device__ __forceinline__ bf16 f2b(float v){ return __float2bfloat16(v); }
__device__ __forceinline__ short f2s(float v){
  bf16 h = __float2bfloat16(v);
  return *reinterpret_cast<short*>(&h);
}

// ---------------------------------------------------------------- LN stats
__global__ __launch_bounds__(256) void ln_stats_kernel(
    const float* __restrict__ x, float* __restrict__ mu, float* __restrict__ rstd)
{
  int tok  = blockIdx.x*4 + (threadIdx.x>>6);
  int lane = threadIdx.x & 63;
  const float4* xr = (const float4*)(x + (size_t)tok*CC);
  float4 v = xr[lane];
  float s  = v.x + v.y + v.z + v.w;
  float sq = v.x*v.x + v.y*v.y + v.z*v.z + v.w*v.w;
  #pragma unroll
  for(int off=32; off>=1; off>>=1){
    s  += __shfl_xor(s,  off, 64);
    sq += __shfl_xor(sq, off, 64);
  }
  if(lane==0){
    float m   = s  * (1.f/CC);
    float var = sq * (1.f/CC) - m*m;
    mu[tok]   = m;
    rstd[tok] = rsqrtf(var + 1e-5f);
  }
}

// ------------------------------------------------------------ QKV projection (MFMA)
// grid (6, 18, 10): x = col tile (proj = bx>>1, 128-col half), y = 128-row tile, z = (b,l)
__global__ __launch_bounds__(256) void qkv_gemm_kernel(
    const float* __restrict__ x,  const float* __restrict__ pe,
    const float* __restrict__ mu, const float* __restrict__ rstd,
    const float* __restrict__ lnw, const float* __restrict__ lnb,
    const float* __restrict__ qw, const float* __restrict__ qb,
    const float* __restrict__ kw, const float* __restrict__ kb,
    const float* __restrict__ vw, const float* __restrict__ vb,
    bf16* __restrict__ qkv)
{
  int g = blockIdx.z;
  int t = (int)pe[(size_t)g*HWW*3 + 2];
  int proj   = blockIdx.x >> 1;
  int o_base = (blockIdx.x & 1) * 128;
  const float* wsel = (proj==0 ? qw : (proj==1 ? kw : vw)) + ((size_t)t*INNER + o_base)*CC;
  const float* bsel = (proj==0 ? qb : (proj==1 ? kb : vb)) + t*INNER;
  int row_base = blockIdx.y*128;
  int tid = threadIdx.x;
  int tokbase = g*HWW + row_base;

  __shared__ __align__(16) short A_s[128*64];
  __shared__ __align__(16) short B_s[128*64];

  int wv = tid>>6, lane = tid&63;
  int wr = wv>>1, wc = wv&1;
  int l16 = lane&15, l4 = lane>>4;
  int kc = tid & 7;            // fixed k-chunk (8 elems) for staging
  int rsub = tid >> 3;         // 0..31

  f32x4 acc[4][4];
  #pragma unroll
  for(int i=0;i<4;i++)
    #pragma unroll
    for(int j=0;j<4;j++) acc[i][j] = (f32x4){0.f,0.f,0.f,0.f};

  for(int kk=0; kk<CC; kk+=64){
    if(kk) __syncthreads();
    // ---- stage A (apply LayerNorm, f32 -> bf16), swizzled
    float4 w0 = *(const float4*)(lnw + kk + kc*8);
    float4 w1 = *(const float4*)(lnw + kk + kc*8 + 4);
    float4 c0 = *(const float4*)(lnb + kk + kc*8);
    float4 c1 = *(const float4*)(lnb + kk + kc*8 + 4);
    #pragma unroll
    for(int tt=0; tt<4; tt++){
      int row = rsub + tt*32;
      int tok = tokbase + row;
      float m = mu[tok], rs = rstd[tok];
      const float4* src = (const float4*)(x + (size_t)tok*CC + kk + kc*8);
      float4 xa = src[0], xb = src[1];
      short8 pk;
      pk[0]=f2s((xa.x-m)*rs*w0.x+c0.x); pk[1]=f2s((xa.y-m)*rs*w0.y+c0.y);
      pk[2]=f2s((xa.z-m)*rs*w0.z+c0.z); pk[3]=f2s((xa.w-m)*rs*w0.w+c0.w);
      pk[4]=f2s((xb.x-m)*rs*w1.x+c1.x); pk[5]=f2s((xb.y-m)*rs*w1.y+c1.y);
      pk[6]=f2s((xb.z-m)*rs*w1.z+c1.z); pk[7]=f2s((xb.w-m)*rs*w1.w+c1.w);
      int el = (row*64 + kc*8) ^ ((row&7)<<3);
      *reinterpret_cast<short8*>(&A_s[el]) = pk;
    }
    // ---- stage B (weights f32 -> bf16), swizzled
    #pragma unroll
    for(int tt=0; tt<4; tt++){
      int n = rsub + tt*32;
      const float4* src = (const float4*)(wsel + (size_t)n*CC + kk + kc*8);
      float4 ba = src[0], bb = src[1];
      short8 pk;
      pk[0]=f2s(ba.x); pk[1]=f2s(ba.y); pk[2]=f2s(ba.z); pk[3]=f2s(ba.w);
      pk[4]=f2s(bb.x); pk[5]=f2s(bb.y); pk[6]=f2s(bb.z); pk[7]=f2s(bb.w);
      int el = (n*64 + kc*8) ^ ((n&7)<<3);
      *reinterpret_cast<short8*>(&B_s[el]) = pk;
    }
    __syncthreads();
    // ---- 2 x k32 MFMA rounds
    #pragma unroll
    for(int ks=0; ks<2; ks++){
      short8 af[4], bf[4];
      #pragma unroll
      for(int fr=0; fr<4; fr++){
        int row = wr*64 + fr*16 + l16;
        int el = (row*64 + ks*32 + l4*8) ^ ((row&7)<<3);
        af[fr] = *reinterpret_cast<const short8*>(&A_s[el]);
      }
      #pragma unroll
      for(int fc=0; fc<4; fc++){
        int n = wc*64 + fc*16 + l16;
        int el = (n*64 + ks*32 + l4*8) ^ ((n&7)<<3);
        bf[fc] = *reinterpret_cast<const short8*>(&B_s[el]);
      }
      #pragma unroll
      for(int fr=0; fr<4; fr++)
        #pragma unroll
        for(int fc=0; fc<4; fc++)
          acc[fr][fc] = __builtin_amdgcn_mfma_f32_16x16x32_bf16(af[fr], bf[fc], acc[fr][fc], 0,0,0);
    }
  }
  // ---- epilogue: bias + store bf16
  #pragma unroll
  for(int fr=0; fr<4; fr++){
    #pragma unroll
    for(int fc=0; fc<4; fc++){
      int ocol = o_base + wc*64 + fc*16 + l16;
      float bias = bsel[ocol];
      #pragma unroll
      for(int r=0; r<4; r++){
        int row = row_base + wr*64 + fr*16 + l4*4 + r;
        qkv[((size_t)g*HWW + row)*NPROJ + proj*INNER + ocol] = f2b(acc[fr][fc][r] + bias);
      }
    }
  }
}

// ------------------------------------------------------------ attention core
// block = 256 thr (4 waves); each half-wave (32 lanes = head dim) owns one hw.
// grid = B*HWW/8 = 576
__global__ __launch_bounds__(256) void attn_core_kernel(
    const bf16* __restrict__ qkv, const float* __restrict__ pe,
    const int*  __restrict__ mask,
    const float* __restrict__ ra,  const float* __restrict__ rm,
    bf16* __restrict__ attn_out)
{
  int bid = blockIdx.x;
  int b = bid / (HWW/8);
  int hw_base = (bid % (HWW/8)) * 8;
  int tid = threadIdx.x;
  int wave = tid>>6, lane = tid&63, sub = lane>>5, d = lane&31;
  int hw = hw_base + wave*2 + sub;

  __shared__ float watt[4][DD][DD];
  __shared__ float wmsg[4][DD][DD];
  __shared__ int st[LL];
  if(tid < LL) st[tid] = (int)pe[(size_t)(b*LL+tid)*HWW*3 + 2];

  unsigned mb = 0;
  const int* mrow = mask + ((size_t)b*HWW + hw)*25;
  #pragma unroll
  for(int ij=0; ij<25; ij++) if(mrow[ij]==0) mb |= (1u<<ij);

  for(int m=0; m<MM; m++){
    __syncthreads();
    #pragma unroll
    for(int i=0;i<16;i++){
      int idx = tid + i*256;         // 4096 elems per array
      int r = idx>>10, rem = idx & 1023;
      int p = rem>>5, qd = rem&31;
      size_t src = (((size_t)r*MM + m)*DD + p)*DD + qd;
      watt[r][p][qd] = ra[src];
      wmsg[r][p][qd] = rm[src];
    }
    __syncthreads();

    float qreg[LL], kreg[LL], vreg[LL];
    #pragma unroll
    for(int l=0;l<LL;l++){
      size_t base = ((size_t)(b*LL+l)*HWW + hw)*NPROJ + m*DD + d;
      qreg[l] = b2f(qkv[base]);
      kreg[l] = b2f(qkv[base+256]);
      vreg[l] = b2f(qkv[base+512]);
    }

    float qWa[LL][2], vWm[LL][2];
    #pragma unroll
    for(int i=0;i<LL;i++){ qWa[i][0]=0.f; qWa[i][1]=0.f; vWm[i][0]=0.f; vWm[i][1]=0.f; }

    #pragma unroll
    for(int i=0;i<LL;i++){
      int r0 = st[i]*2;              // rel = 2*t_i + tj
      #pragma unroll
      for(int p=0;p<DD;p++){
        float qp = __shfl(qreg[i], p, 32);
        qWa[i][0] += qp * watt[r0  ][p][d];
        qWa[i][1] += qp * watt[r0+1][p][d];
      }
    }
    #pragma unroll
    for(int j=0;j<LL;j++){
      int tj = st[j];                // rel = 2*ti + t_j
      #pragma unroll
      for(int p=0;p<DD;p++){
        float vp = __shfl(vreg[j], p, 32);
        vWm[j][0] += vp * wmsg[tj  ][p][d];
        vWm[j][1] += vp * wmsg[2+tj][p][d];
      }
    }

    #pragma unroll
    for(int i=0;i<LL;i++){
      float attv[LL];
      #pragma unroll
      for(int j=0;j<LL;j++){
        float part = qWa[i][st[j]] * kreg[j];
        #pragma unroll
        for(int off=16; off>=1; off>>=1) part += __shfl_xor(part, off, 32);
        attv[j] = (mb & (1u<<(i*5+j))) ? -1e9f : part*SCALE_ATT;
      }
      float mx = attv[0];
      #pragma unroll
      for(int j=1;j<LL;j++) mx = fmaxf(mx, attv[j]);
      float ssum = 0.f;
      #pragma unroll
      for(int j=0;j<LL;j++){ attv[j] = __expf(attv[j]-mx); ssum += attv[j]; }
      float inv = 1.f/ssum;
      float o = 0.f;
      int ti = st[i];
      #pragma unroll
      for(int j=0;j<LL;j++) o += attv[j]*vWm[j][ti];
      o *= inv;
      attn_out[(((size_t)b*HWW + hw)*LL + i)*CC + m*DD + d] = f2b(o);
    }
  }
}

// ------------------------------------------------------- output projection (MFMA)
// grid (2, 18, 10): x = 128-col tile, y = 128-row tile, z = (b,l)
__global__ __launch_bounds__(256) void out_gemm_kernel(
    const bf16* __restrict__ attn_out, const float* __restrict__ pe,
    const float* __restrict__ aw, const float* __restrict__ ab,
    float* __restrict__ out)
{
  int g = blockIdx.z; int b = g/LL, l = g%LL;
  int t = (int)pe[(size_t)g*HWW*3 + 2];
  int o_base = blockIdx.x*128;
  int row_base = blockIdx.y*128;
  int tid = threadIdx.x;
  const float* wsel = aw + ((size_t)t*CC + o_base)*CC;

  __shared__ __align__(16) short A_s[128*64];
  __shared__ __align__(16) short B_s[128*64];

  int wv = tid>>6, lane = tid&63;
  int wr = wv>>1, wc = wv&1;
  int l16 = lane&15, l4 = lane>>4;
  int kc = tid & 7;
  int rsub = tid >> 3;

  f32x4 acc[4][4];
  #pragma unroll
  for(int i=0;i<4;i++)
    #pragma unroll
    for(int j=0;j<4;j++) acc[i][j] = (f32x4){0.f,0.f,0.f,0.f};

  for(int kk=0; kk<CC; kk+=64){
    if(kk) __syncthreads();
    // ---- stage A (bf16 source, direct 16B copy), swizzled
    #pragma unroll
    for(int tt=0; tt<4; tt++){
      int row = rsub + tt*32;
      short8 pk = *reinterpret_cast<const short8*>(
          attn_out + (((size_t)(b*HWW) + row_base + row)*LL + l)*CC + kk + kc*8);
      int el = (row*64 + kc*8) ^ ((row&7)<<3);
      *reinterpret_cast<short8*>(&A_s[el]) = pk;
    }
    // ---- stage B (weights f32 -> bf16), swizzled
    #pragma unroll
    for(int tt=0; tt<4; tt++){
      int n = rsub + tt*32;
      const float4* src = (const float4*)(wsel + (size_t)n*CC + kk + kc*8);
      float4 ba = src[0], bb = src[1];
      short8 pk;
      pk[0]=f2s(ba.x); pk[1]=f2s(ba.y); pk[2]=f2s(ba.z); pk[3]=f2s(ba.w);
      pk[4]=f2s(bb.x); pk[5]=f2s(bb.y); pk[6]=f2s(bb.z); pk[7]=f2s(bb.w);
      int el = (n*64 + kc*8) ^ ((n&7)<<3);
      *reinterpret_cast<short8*>(&B_s[el]) = pk;
    }
    __syncthreads();
    #pragma unroll
    for(int ks=0; ks<2; ks++){
      short8 af[4], bf[4];
      #pragma unroll
      for(int fr=0; fr<4; fr++){
        int row = wr*64 + fr*16 + l16;
        int el = (row*64 + ks*32 + l4*8) ^ ((row&7)<<3);
        af[fr] = *reinterpret_cast<const short8*>(&A_s[el]);
      }
      #pragma unroll
      for(int fc=0; fc<4; fc++){
        int n = wc*64 + fc*16 + l16;
        int el = (n*64 + ks*32 + l4*8) ^ ((n&7)<<3);
        bf[fc] = *reinterpret_cast<const short8*>(&B_s[el]);
      }
      #pragma unroll
      for(int fr=0; fr<4; fr++)
        #pragma unroll
        for(int fc=0; fc<4; fc++)
          acc[fr][fc] = __builtin_amdgcn_mfma_f32_16x16x32_bf16(af[fr], bf[fc], acc[fr][fc], 0,0,0);
    }
  }
  // ---- epilogue: bias + store f32
  #pragma unroll
  for(int fr=0; fr<4; fr++){
    #pragma unroll
    for(int fc=0; fc<4; fc++){
      int ocol = o_base + wc*64 + fc*16 + l16;
      float bias = ab[t*CC + ocol];
      #pragma unroll
      for(int r=0; r<4; r++){
        int row = row_base + wr*64 + fr*16 + l4*4 + r;
        out[((size_t)g*HWW + row)*CC + ocol] = acc[fr][fc][r] + bias;
      }
    }
  }
}

// ------------------------------------------------------------------ launch
extern "C" void kernel_launch(void* const* d_in, const int* in_sizes, int n_in,
                              void* d_out, int out_size, void* d_ws, size_t ws_size,
                              hipStream_t stream)
{
  const float* x   = (const float*)d_in[0];
  const int*   mask= (const int*)  d_in[1];
  const float* pe  = (const float*)d_in[2];
  const float* lnw = (const float*)d_in[3];
  const float* lnb = (const float*)d_in[4];
  const float* qw  = (const float*)d_in[5];
  const float* qb  = (const float*)d_in[6];
  const float* kw  = (const float*)d_in[7];
  const float* kb  = (const float*)d_in[8];
  const float* vw  = (const float*)d_in[9];
  const float* vb  = (const float*)d_in[10];
  const float* aw  = (const float*)d_in[11];
  const float* ab  = (const float*)d_in[12];
  const float* ra  = (const float*)d_in[13];
  const float* rm  = (const float*)d_in[14];

  char* ws = (char*)d_ws;
  float* mu   = (float*)ws;                         // 23040 f32
  float* rstd = (float*)(ws + 92160);               // 23040 f32
  bf16*  qkv  = (bf16*)(ws + 184320);               // 10*2304*768 bf16
  bf16*  attn = (bf16*)(ws + 184320 + 35389440);    // 2*2304*5*256 bf16
  float* out  = (float*)d_out;

  hipLaunchKernelGGL(ln_stats_kernel, dim3(NTOK/4), dim3(256), 0, stream, x, mu, rstd);
  hipLaunchKernelGGL(qkv_gemm_kernel, dim3(6, 18, 10), dim3(256), 0, stream,
                     x, pe, mu, rstd, lnw, lnb, qw, qb, kw, kb, vw, vb, qkv);
  hipLaunchKernelGGL(attn_core_kernel, dim3(BB*HWW/8), dim3(256), 0, stream,
                     qkv, pe, mask, ra, rm, attn);
  hipLaunchKernelGGL(out_gemm_kernel, dim3(2, 18, 10), dim3(256), 0, stream,
                     attn, pe, aw, ab, out);
}

// Round 9
// 209.776 us; speedup vs baseline: 1.6721x; 1.6721x over previous
//
#include <hip/hip_runtime.h>
#include <hip/hip_bf16.h>

#define BB 2
#define LL 5
#define HH 48
#define WW 48
#define CC 256
#define MM 8
#define DD 32
#define HWW (HH*WW)        // 2304
#define NTOK (BB*LL*HWW)   // 23040
#define INNER 256
#define NOUT 1280          // qa(512) | k(256) | vm(512)
#define SCALE_ATT 0.17677669529663687f

typedef __hip_bfloat16 bf16;
typedef short short8 __attribute__((ext_vector_type(8)));
typedef float f32x4  __attribute__((ext_vector_type(4)));

__device__ __forceinline__ float b2f(bf16 v){ return __bfloat162float(v); }
__device__ __forceinline__ bf16 f2b(float v){ return __float2bfloat16(v); }
__device__ __forceinline__ short f2s(float v){
  bf16 h = __float2bfloat16(v);
  return *reinterpret_cast<short*>(&h);
}

// ---------------------------------------------------------------- LN stats
__global__ __launch_bounds__(256) void ln_stats_kernel(
    const float* __restrict__ x, float* __restrict__ mu, float* __restrict__ rstd)
{
  int tok  = blockIdx.x*4 + (threadIdx.x>>6);
  int lane = threadIdx.x & 63;
  const float4* xr = (const float4*)(x + (size_t)tok*CC);
  float4 v = xr[lane];
  float s  = v.x + v.y + v.z + v.w;
  float sq = v.x*v.x + v.y*v.y + v.z*v.z + v.w*v.w;
  #pragma unroll
  for(int off=32; off>=1; off>>=1){
    s  += __shfl_xor(s,  off, 64);
    sq += __shfl_xor(sq, off, 64);
  }
  if(lane==0){
    float m   = s  * (1.f/CC);
    float var = sq * (1.f/CC) - m*m;
    mu[tok]   = m;
    rstd[tok] = rsqrtf(var + 1e-5f);
  }
}

// ------------------------------------------------- composite weight build
// W_all[t][n][c], n in [0,1280):
//   n<512   : qa  s=n>>8, m=(n&255)>>5, d'=n&31 : sum_p Wq[t][m*32+p][c]*ra[2t+s][m][p][d']
//   n<768   : k   o=n-512 : Wk[t][o][c]
//   else    : vm  s=(n-768)>>8 : sum_p Wv[t][m*32+p][c]*rm[2s+t][m][p][c']
// grid 640 = t(2) x 320 blocks; wave handles one n row; lane owns 4 c.
__global__ __launch_bounds__(256) void wcomp_kernel(
    const float* __restrict__ qw, const float* __restrict__ qb,
    const float* __restrict__ kw, const float* __restrict__ kb,
    const float* __restrict__ vw, const float* __restrict__ vb,
    const float* __restrict__ ra, const float* __restrict__ rm,
    bf16* __restrict__ W_all, float* __restrict__ b_all)
{
  int bid = blockIdx.x;
  int t = bid / 320, nb = bid % 320;
  int tid = threadIdx.x;
  int wv = tid>>6, lane = tid&63;
  int n = nb*4 + wv;

  float a0=0.f,a1=0.f,a2=0.f,a3=0.f, bias=0.f;
  if(n < 512 || n >= 768){
    bool isq = (n < 512);
    int nr = isq ? n : n-768;
    int s = nr>>8, mdp = nr&255, m = mdp>>5, dp = mdp&31;
    int r = isq ? (2*t+s) : (2*s+t);
    const float* rel  = (isq ? ra : rm) + ((size_t)r*MM + m)*DD*DD + dp;     // [p] stride DD
    const float* wrow = (isq ? qw : vw) + (size_t)t*INNER*CC + (size_t)m*DD*CC;
    const float* brow = (isq ? qb : vb) + t*INNER + m*DD;
    #pragma unroll
    for(int p=0;p<DD;p++){
      float rv = rel[p*DD];
      float4 w4 = *(const float4*)(wrow + p*CC + lane*4);
      a0 += w4.x*rv; a1 += w4.y*rv; a2 += w4.z*rv; a3 += w4.w*rv;
      bias += brow[p]*rv;
    }
  } else {
    int o = n - 512;
    float4 w4 = *(const float4*)(kw + (size_t)t*INNER*CC + (size_t)o*CC + lane*4);
    a0=w4.x; a1=w4.y; a2=w4.z; a3=w4.w;
    bias = kb[t*INNER + o];
  }
  bf16* dst = W_all + ((size_t)t*NOUT + n)*CC + lane*4;
  dst[0]=f2b(a0); dst[1]=f2b(a1); dst[2]=f2b(a2); dst[3]=f2b(a3);
  if(lane==0) b_all[t*NOUT + n] = bias;
}

// ------------------------------------------------------------ qa/k/vm GEMM (MFMA)
// grid (10, 18, 10): x = 128-col tile of 1280, y = 128-row tile, z = (b,l)
__global__ __launch_bounds__(256) void qkvm_gemm_kernel(
    const float* __restrict__ x,  const float* __restrict__ pe,
    const float* __restrict__ mu, const float* __restrict__ rstd,
    const float* __restrict__ lnw, const float* __restrict__ lnb,
    const bf16* __restrict__ W_all, const float* __restrict__ b_all,
    bf16* __restrict__ qkvm)
{
  int g = blockIdx.z;
  int t = (int)pe[(size_t)g*HWW*3 + 2];
  int o_base = blockIdx.x * 128;
  const bf16*  wsel = W_all + ((size_t)t*NOUT + o_base)*CC;
  const float* bsel = b_all + t*NOUT;
  int row_base = blockIdx.y*128;
  int tid = threadIdx.x;
  int tokbase = g*HWW + row_base;

  __shared__ __align__(16) short A_s[128*64];
  __shared__ __align__(16) short B_s[128*64];

  int wv = tid>>6, lane = tid&63;
  int wr = wv>>1, wc = wv&1;
  int l16 = lane&15, l4 = lane>>4;
  int kc = tid & 7;            // fixed k-chunk (8 elems) for staging
  int rsub = tid >> 3;         // 0..31

  f32x4 acc[4][4];
  #pragma unroll
  for(int i=0;i<4;i++)
    #pragma unroll
    for(int j=0;j<4;j++) acc[i][j] = (f32x4){0.f,0.f,0.f,0.f};

  for(int kk=0; kk<CC; kk+=64){
    if(kk) __syncthreads();
    // ---- stage A (apply LayerNorm, f32 -> bf16), swizzled
    float4 w0 = *(const float4*)(lnw + kk + kc*8);
    float4 w1 = *(const float4*)(lnw + kk + kc*8 + 4);
    float4 c0 = *(const float4*)(lnb + kk + kc*8);
    float4 c1 = *(const float4*)(lnb + kk + kc*8 + 4);
    #pragma unroll
    for(int tt=0; tt<4; tt++){
      int row = rsub + tt*32;
      int tok = tokbase + row;
      float m = mu[tok], rs = rstd[tok];
      const float4* src = (const float4*)(x + (size_t)tok*CC + kk + kc*8);
      float4 xa = src[0], xb = src[1];
      short8 pk;
      pk[0]=f2s((xa.x-m)*rs*w0.x+c0.x); pk[1]=f2s((xa.y-m)*rs*w0.y+c0.y);
      pk[2]=f2s((xa.z-m)*rs*w0.z+c0.z); pk[3]=f2s((xa.w-m)*rs*w0.w+c0.w);
      pk[4]=f2s((xb.x-m)*rs*w1.x+c1.x); pk[5]=f2s((xb.y-m)*rs*w1.y+c1.y);
      pk[6]=f2s((xb.z-m)*rs*w1.z+c1.z); pk[7]=f2s((xb.w-m)*rs*w1.w+c1.w);
      int el = (row*64 + kc*8) ^ ((row&7)<<3);
      *reinterpret_cast<short8*>(&A_s[el]) = pk;
    }
    // ---- stage B (bf16 composite weights, direct copy), swizzled
    #pragma unroll
    for(int tt=0; tt<4; tt++){
      int n = rsub + tt*32;
      short8 pk = *reinterpret_cast<const short8*>(wsel + (size_t)n*CC + kk + kc*8);
      int el = (n*64 + kc*8) ^ ((n&7)<<3);
      *reinterpret_cast<short8*>(&B_s[el]) = pk;
    }
    __syncthreads();
    // ---- 2 x k32 MFMA rounds
    #pragma unroll
    for(int ks=0; ks<2; ks++){
      short8 af[4], bfr[4];
      #pragma unroll
      for(int fr=0; fr<4; fr++){
        int row = wr*64 + fr*16 + l16;
        int el = (row*64 + ks*32 + l4*8) ^ ((row&7)<<3);
        af[fr] = *reinterpret_cast<const short8*>(&A_s[el]);
      }
      #pragma unroll
      for(int fc=0; fc<4; fc++){
        int n = wc*64 + fc*16 + l16;
        int el = (n*64 + ks*32 + l4*8) ^ ((n&7)<<3);
        bfr[fc] = *reinterpret_cast<const short8*>(&B_s[el]);
      }
      #pragma unroll
      for(int fr=0; fr<4; fr++)
        #pragma unroll
        for(int fc=0; fc<4; fc++)
          acc[fr][fc] = __builtin_amdgcn_mfma_f32_16x16x32_bf16(af[fr], bfr[fc], acc[fr][fc], 0,0,0);
    }
  }
  // ---- epilogue: bias + store bf16
  #pragma unroll
  for(int fr=0; fr<4; fr++){
    #pragma unroll
    for(int fc=0; fc<4; fc++){
      int ocol = o_base + wc*64 + fc*16 + l16;
      float bias = bsel[ocol];
      #pragma unroll
      for(int r=0; r<4; r++){
        int row = row_base + wr*64 + fr*16 + l4*4 + r;
        qkvm[((size_t)g*HWW + row)*NOUT + ocol] = f2b(acc[fr][fc][r] + bias);
      }
    }
  }
}

// ------------------------------------------------------------ attention lite
// grid = B*HWW = 4608 blocks; block 256 thr; half-wave (32 lanes = d) = one head.
__global__ __launch_bounds__(256) void attn_lite_kernel(
    const bf16* __restrict__ qkvm, const float* __restrict__ pe,
    const int*  __restrict__ mask, bf16* __restrict__ attn_out)
{
  int pix = blockIdx.x;
  int b = pix / HWW, hw = pix - b*HWW;
  int tid = threadIdx.x;
  int m = tid>>5, d = tid&31;

  __shared__ int st[LL];
  __shared__ unsigned mbS;
  if(tid==0) mbS = 0u;
  if(tid<LL) st[tid] = (int)pe[(size_t)(b*LL+tid)*HWW*3 + 2];
  __syncthreads();
  const int* mrow = mask + ((size_t)b*HWW + hw)*25;
  if(tid<25 && mrow[tid]==0) atomicOr(&mbS, 1u<<tid);
  __syncthreads();
  unsigned mb = mbS;

  float qa[LL][2], kv[LL], vm[LL][2];
  #pragma unroll
  for(int l=0;l<LL;l++){
    size_t base = ((size_t)(b*LL+l)*HWW + hw)*NOUT + m*DD + d;
    qa[l][0] = b2f(qkvm[base]);
    qa[l][1] = b2f(qkvm[base+256]);
    kv[l]    = b2f(qkvm[base+512]);
    vm[l][0] = b2f(qkvm[base+768]);
    vm[l][1] = b2f(qkvm[base+1024]);
  }

  float p[LL][LL];
  #pragma unroll
  for(int i=0;i<LL;i++){
    #pragma unroll
    for(int j=0;j<LL;j++){
      int stj = st[j];
      float part = (stj ? qa[i][1] : qa[i][0]) * kv[j];
      #pragma unroll
      for(int off=16; off>=1; off>>=1) part += __shfl_xor(part, off, 32);
      p[i][j] = (mb & (1u<<(i*5+j))) ? -1e9f : part*SCALE_ATT;
    }
  }
  #pragma unroll
  for(int i=0;i<LL;i++){
    float mx = p[i][0];
    #pragma unroll
    for(int j=1;j<LL;j++) mx = fmaxf(mx, p[i][j]);
    float ssum = 0.f;
    #pragma unroll
    for(int j=0;j<LL;j++){ p[i][j] = __expf(p[i][j]-mx); ssum += p[i][j]; }
    float inv = 1.f/ssum;
    int sti = st[i];
    float o = 0.f;
    #pragma unroll
    for(int j=0;j<LL;j++) o += p[i][j] * (sti ? vm[j][1] : vm[j][0]);
    o *= inv;
    attn_out[(((size_t)b*HWW + hw)*LL + i)*CC + m*DD + d] = f2b(o);
  }
}

// ------------------------------------------------------- output projection (MFMA)
// grid (2, 18, 10): x = 128-col tile, y = 128-row tile, z = (b,l)
__global__ __launch_bounds__(256) void out_gemm_kernel(
    const bf16* __restrict__ attn_out, const float* __restrict__ pe,
    const float* __restrict__ aw, const float* __restrict__ ab,
    float* __restrict__ out)
{
  int g = blockIdx.z; int b = g/LL, l = g%LL;
  int t = (int)pe[(size_t)g*HWW*3 + 2];
  int o_base = blockIdx.x*128;
  int row_base = blockIdx.y*128;
  int tid = threadIdx.x;
  const float* wsel = aw + ((size_t)t*CC + o_base)*CC;

  __shared__ __align__(16) short A_s[128*64];
  __shared__ __align__(16) short B_s[128*64];

  int wv = tid>>6, lane = tid&63;
  int wr = wv>>1, wc = wv&1;
  int l16 = lane&15, l4 = lane>>4;
  int kc = tid & 7;
  int rsub = tid >> 3;

  f32x4 acc[4][4];
  #pragma unroll
  for(int i=0;i<4;i++)
    #pragma unroll
    for(int j=0;j<4;j++) acc[i][j] = (f32x4){0.f,0.f,0.f,0.f};

  for(int kk=0; kk<CC; kk+=64){
    if(kk) __syncthreads();
    // ---- stage A (bf16 source, direct 16B copy), swizzled
    #pragma unroll
    for(int tt=0; tt<4; tt++){
      int row = rsub + tt*32;
      short8 pk = *reinterpret_cast<const short8*>(
          attn_out + (((size_t)(b*HWW) + row_base + row)*LL + l)*CC + kk + kc*8);
      int el = (row*64 + kc*8) ^ ((row&7)<<3);
      *reinterpret_cast<short8*>(&A_s[el]) = pk;
    }
    // ---- stage B (weights f32 -> bf16), swizzled
    #pragma unroll
    for(int tt=0; tt<4; tt++){
      int n = rsub + tt*32;
      const float4* src = (const float4*)(wsel + (size_t)n*CC + kk + kc*8);
      float4 ba = src[0], bb = src[1];
      short8 pk;
      pk[0]=f2s(ba.x); pk[1]=f2s(ba.y); pk[2]=f2s(ba.z); pk[3]=f2s(ba.w);
      pk[4]=f2s(bb.x); pk[5]=f2s(bb.y); pk[6]=f2s(bb.z); pk[7]=f2s(bb.w);
      int el = (n*64 + kc*8) ^ ((n&7)<<3);
      *reinterpret_cast<short8*>(&B_s[el]) = pk;
    }
    __syncthreads();
    #pragma unroll
    for(int ks=0; ks<2; ks++){
      short8 af[4], bfr[4];
      #pragma unroll
      for(int fr=0; fr<4; fr++){
        int row = wr*64 + fr*16 + l16;
        int el = (row*64 + ks*32 + l4*8) ^ ((row&7)<<3);
        af[fr] = *reinterpret_cast<const short8*>(&A_s[el]);
      }
      #pragma unroll
      for(int fc=0; fc<4; fc++){
        int n = wc*64 + fc*16 + l16;
        int el = (n*64 + ks*32 + l4*8) ^ ((n&7)<<3);
        bfr[fc] = *reinterpret_cast<const short8*>(&B_s[el]);
      }
      #pragma unroll
      for(int fr=0; fr<4; fr++)
        #pragma unroll
        for(int fc=0; fc<4; fc++)
          acc[fr][fc] = __builtin_amdgcn_mfma_f32_16x16x32_bf16(af[fr], bfr[fc], acc[fr][fc], 0,0,0);
    }
  }
  // ---- epilogue: bias + store f32
  #pragma unroll
  for(int fr=0; fr<4; fr++){
    #pragma unroll
    for(int fc=0; fc<4; fc++){
      int ocol = o_base + wc*64 + fc*16 + l16;
      float bias = ab[t*CC + ocol];
      #pragma unroll
      for(int r=0; r<4; r++){
        int row = row_base + wr*64 + fr*16 + l4*4 + r;
        out[((size_t)g*HWW + row)*CC + ocol] = acc[fr][fc][r] + bias;
      }
    }
  }
}

// ------------------------------------------------------------------ launch
extern "C" void kernel_launch(void* const* d_in, const int* in_sizes, int n_in,
                              void* d_out, int out_size, void* d_ws, size_t ws_size,
                              hipStream_t stream)
{
  const float* x   = (const float*)d_in[0];
  const int*   mask= (const int*)  d_in[1];
  const float* pe  = (const float*)d_in[2];
  const float* lnw = (const float*)d_in[3];
  const float* lnb = (const float*)d_in[4];
  const float* qw  = (const float*)d_in[5];
  const float* qb  = (const float*)d_in[6];
  const float* kw  = (const float*)d_in[7];
  const float* kb  = (const float*)d_in[8];
  const float* vw  = (const float*)d_in[9];
  const float* vb  = (const float*)d_in[10];
  const float* aw  = (const float*)d_in[11];
  const float* ab  = (const float*)d_in[12];
  const float* ra  = (const float*)d_in[13];
  const float* rm  = (const float*)d_in[14];

  char* ws = (char*)d_ws;
  float* mu    = (float*)ws;                          //   92,160 B
  float* rstd  = (float*)(ws + 92160);                //   92,160 B
  bf16*  W_all = (bf16*) (ws + 184320);               //  1,310,720 B (2x1280x256 bf16)
  float* b_all = (float*)(ws + 1495040);              //     10,240 B
  bf16*  qkvm  = (bf16*) (ws + 1505280);              // 58,982,400 B (23040x1280 bf16)
  bf16*  attn  = (bf16*) (ws + 60487680);             // 11,796,480 B
  float* out   = (float*)d_out;

  hipLaunchKernelGGL(ln_stats_kernel, dim3(NTOK/4), dim3(256), 0, stream, x, mu, rstd);
  hipLaunchKernelGGL(wcomp_kernel, dim3(640), dim3(256), 0, stream,
                     qw, qb, kw, kb, vw, vb, ra, rm, W_all, b_all);
  hipLaunchKernelGGL(qkvm_gemm_kernel, dim3(10, 18, 10), dim3(256), 0, stream,
                     x, pe, mu, rstd, lnw, lnb, W_all, b_all, qkvm);
  hipLaunchKernelGGL(attn_lite_kernel, dim3(BB*HWW), dim3(256), 0, stream,
                     qkvm, pe, mask, attn);
  hipLaunchKernelGGL(out_gemm_kernel, dim3(2, 18, 10), dim3(256), 0, stream,
                     attn, pe, aw, ab, out);
}